// Round 9
// baseline (141.654 us; speedup 1.0000x reference)
//
#include <hip/hip_runtime.h>
#include <hip/hip_fp16.h>
#include <stdint.h>

// Problem constants (fixed by reference file)
#define TOKENS 65536   // T*B = 2048*32
#define D      128
#define NEXP   9       // MULTI_INFER_NUM + 1
#define MT     16      // tokens per tile; block = 4 waves x (16 rows x 32 cols)
#define NTILES (TOKENS / MT)   // 4096 = exactly 2 generations at 8 blocks/CU
#define NHB    256     // hist blocks (TOKENS/256)

typedef _Float16 f16;
typedef _Float16 f16x8  __attribute__((ext_vector_type(8)));
typedef float    f32x4  __attribute__((ext_vector_type(4)));
typedef uint32_t u32;
typedef unsigned long long u64;

// ---- workspace layout (int32 indices) ----
#define WI_TOKOFF  32            // [10] exclusive token offsets per expert
#define WI_HIST    128           // [256][9]
#define WI_PERM    4736          // [TOKENS]
#define WS_WF_OFF  ((4736 + TOKENS) * 4)   // f16 Wfrag[72][16384], 16B-aligned

#define LOG2E  1.44269504f

// ---- fused prep: fragment-major f16 weights for 16x16x32 (blocks 0..287) + hist (288..543) ----
// Wf[mat][c(8)][kb(4)][lane(64)][i(8)], lane = quad*16 + n:
//   element = Ws[mat][d = kb*32 + quad*8 + i][f = c*16 + n]
__global__ void k_prep(const float* __restrict__ Ws, const int* __restrict__ pos,
                       int* __restrict__ wsI, f16* __restrict__ Wf) {
  const int tid = threadIdx.x;
  if (blockIdx.x < 288) {
    const int mat = blockIdx.x >> 2;      // 0..71
    const int q   = blockIdx.x & 3;
    const float* src = Ws + (size_t)mat * (D * D);
    f16* dst = Wf + (size_t)mat * (D * D);
#pragma unroll
    for (int p = 0; p < 2; ++p) {
      int cc = q * 512 + p * 256 + tid;   // 16B chunk index 0..2047 = ((c*4+kb)*64 + lane)
      int ln = cc & 63;
      int kb = (cc >> 6) & 3;
      int c  = cc >> 8;
      int quad = ln >> 4, n = ln & 15;
      int f  = c * 16 + n;
      int d0 = kb * 32 + quad * 8;
      f16x8 w;
#pragma unroll
      for (int i = 0; i < 8; ++i) w[i] = (f16)src[(d0 + i) * D + f];
      *(f16x8*)(dst + cc * 8) = w;
    }
  } else {
    const int b = blockIdx.x - 288;
    __shared__ int h[NEXP];
    if (tid < NEXP) h[tid] = 0;
    __syncthreads();
    int e = pos[b * 256 + tid]; e = e < 8 ? e : 8;
    atomicAdd(&h[e], 1);
    __syncthreads();
    if (tid < NEXP) wsI[WI_HIST + b * NEXP + tid] = h[tid];
  }
}

// ---- assignment WITH fused scan: each block derives expert totals + its own prefix
//      from the histogram (no separate k_scan launch, no global atomics) ----
__global__ void k_assign(const int* __restrict__ pos, int* __restrict__ wsI) {
  const int tid = threadIdx.x, b = blockIdx.x;
  const int lane = tid & 63, w = tid >> 6;
  __shared__ int redF[4], redP[4];
  __shared__ int totS[NEXP], relS[NEXP];
  __shared__ int waveCnt[4][NEXP];
  __shared__ int waveBase[4][NEXP];

  // per-expert: total over all 256 hist blocks + prefix over blocks < b
#pragma unroll 1
  for (int e = 0; e < NEXP; ++e) {
    int v  = wsI[WI_HIST + tid * NEXP + e];
    int vp = (tid < b) ? v : 0;
#pragma unroll
    for (int off = 32; off; off >>= 1) {
      v  += __shfl_down(v, off);
      vp += __shfl_down(vp, off);
    }
    if (lane == 0) { redF[w] = v; redP[w] = vp; }
    __syncthreads();
    if (tid == 0) {
      totS[e] = redF[0] + redF[1] + redF[2] + redF[3];
      relS[e] = redP[0] + redP[1] + redP[2] + redP[3];
    }
    __syncthreads();
  }

  // block 0 publishes expert token offsets for k_main
  if (b == 0 && tid == 0) {
    int tok = 0; wsI[WI_TOKOFF] = 0;
#pragma unroll
    for (int e = 0; e < NEXP; ++e) { tok += totS[e]; wsI[WI_TOKOFF + e + 1] = tok; }
  }

  int e = pos[b * 256 + tid]; e = e < 8 ? e : 8;
  int myRank = 0;
#pragma unroll
  for (int ee = 0; ee < NEXP; ++ee) {
    u64 m = __ballot(e == ee);
    if (e == ee) myRank = __popcll(m & ((1ull << lane) - 1ull));
    if (lane == 0) waveCnt[w][ee] = __popcll(m);
  }
  __syncthreads();
  if (tid < NEXP) {
    int s = 0;
#pragma unroll
    for (int w2 = 0; w2 < 4; ++w2) { waveBase[w2][tid] = s; s += waveCnt[w2][tid]; }
  }
  __syncthreads();
  int tokoff = 0;
#pragma unroll
  for (int k = 0; k < NEXP; ++k) tokoff += (k < e) ? totS[k] : 0;
  wsI[WI_PERM + tokoff + relS[e] + waveBase[w][e] + myRank] = b * 256 + tid;
}

// ---- fused main: 256 thr = 4 waves, each 16 rows x 32 cols; unified regs <= 64
//      (acc 16 AGPR + ~48 arch) => 8 waves/SIMD tier. Grid exactly 4096 = 2 generations.
//      Single-buffered B in K-halves (TLP hides latency at 8 waves/SIMD). ----
__launch_bounds__(256, 8)
__global__ void k_main(const float* __restrict__ xin, const float* __restrict__ bsPtr,
                       const int* __restrict__ wsI, const f16* __restrict__ Wf,
                       float* __restrict__ outPtr) {
  __shared__ __attribute__((aligned(16))) f16 Ash[MT][136];   // 16 x 272B = 4.3 KB
  __shared__ int s_tok[MT];
  __shared__ int s_e[MT];
  __shared__ int s_list[NEXP];
  __shared__ int s_npass;

  const int tid = threadIdx.x;
  const int bid = blockIdx.x;                 // 0..4095, tile = rows bid*16..+15 of perm
  const int lane = tid & 63;

  // ---- wave 0 (lanes 0..15 = rows): token ids, per-row expert, distinct-expert run list ----
  if (tid < 64) {
    int row = bid * MT + (lane & 15);
    int tok0 = wsI[WI_PERM + row];
    int ee = 0;
#pragma unroll
    for (int k = 1; k < NEXP; ++k) ee += (row >= wsI[WI_TOKOFF + k]);
    if (lane < 16) { s_tok[lane] = tok0; s_e[lane] = ee; }
    int eprev = __shfl_up(ee, 1);
    bool newrun = (lane < 16) && (lane == 0 || ee != eprev);
    u64 runs = __ballot(newrun);
    if (newrun) s_list[__popcll(runs & ((1ull << lane) - 1ull))] = ee;
    if (lane == 0) s_npass = (int)__popcll(runs);
  }

  // ---- stage A (16 rows) as f16 via perm gather ----
  {
    int m = tid >> 4, h = tid & 15;           // thread covers cols h*8..h*8+7
    int tok = wsI[WI_PERM + bid * MT + m];
    const float4* src = (const float4*)(xin + (size_t)tok * D + h * 8);
    float4 a = src[0], b2 = src[1];
    f16x8 wv;
    wv[0] = (f16)a.x;  wv[1] = (f16)a.y;  wv[2] = (f16)a.z;  wv[3] = (f16)a.w;
    wv[4] = (f16)b2.x; wv[5] = (f16)b2.y; wv[6] = (f16)b2.z; wv[7] = (f16)b2.w;
    *(f16x8*)&Ash[m][h * 8] = wv;
  }
  __syncthreads();   // barrier 1: Ash, s_tok, s_e, s_list staged

  const int n    = lane & 15;       // MFMA col
  const int quad = lane >> 4;       // k-quad / row-quad
  const int cBase = (tid >> 6) * 2; // wave's first 16-col chunk (4 waves cover 128 cols)
  const int vlane = lane * 8;       // B-frag lane offset (f16 elems)
  const int npass = __builtin_amdgcn_readfirstlane(s_npass);

  f16x8 aF[4];                      // A fragments: 16 rows, full K=128 (16 VGPR)
  f32x4 acc[4];                     // 4 gates (16 AGPR)

#define LOAD_AF()                                                              \
  do {                                                                         \
    _Pragma("unroll")                                                          \
    for (int _kb = 0; _kb < 4; ++_kb)                                          \
      aF[_kb] = *(const f16x8*)&Ash[n][_kb * 32 + quad * 8];                   \
  } while (0)

#pragma unroll 1
  for (int p = 0; p < npass; ++p) {
    const int E = __builtin_amdgcn_readfirstlane(s_list[p]);
    const f16* We = Wf + (size_t)E * 16384;       // mat stride = 9*16384 = 147456
    // 16-bit row mask: bit m set iff row m belongs to expert E
    const u32 rowmask = (u32)__ballot(lane < 16 && s_e[lane] == E);
    const u32 mybits = (rowmask >> (quad * 4)) & 0xF;

    LOAD_AF();
    __syncthreads();   // pass barrier A: all aF(l=0) read before any epilogue Ash write

#pragma unroll 1
    for (int l = 0; l < 2; l++) {
#pragma unroll 1
      for (int ci = 0; ci < 2; ci++) {
        const int cc = cBase + ci;
        const int f = cc * 16 + n;
        float bias[4];
#pragma unroll
        for (int j = 0; j < 4; j++)
          bias[j] = bsPtr[((l * 4 + j) * NEXP + E) * D + f];

        // 4 gate GEMMs, B single-buffered in K-halves (8 VGPR of B live)
#pragma unroll
        for (int j = 0; j < 4; j++) {
          const f16* bp = We + (l * 4 + j) * 147456 + cc * 2048 + vlane;
          f16x8 u0 = *(const f16x8*)bp;
          f16x8 u1 = *(const f16x8*)(bp + 512);
          f32x4 a = {0.f, 0.f, 0.f, 0.f};
          a = __builtin_amdgcn_mfma_f32_16x16x32_f16(aF[0], u0, a, 0, 0, 0);
          a = __builtin_amdgcn_mfma_f32_16x16x32_f16(aF[1], u1, a, 0, 0, 0);
          u0 = *(const f16x8*)(bp + 1024);
          u1 = *(const f16x8*)(bp + 1536);
          a = __builtin_amdgcn_mfma_f32_16x16x32_f16(aF[2], u0, a, 0, 0, 0);
          a = __builtin_amdgcn_mfma_f32_16x16x32_f16(aF[3], u1, a, 0, 0, 0);
          acc[j] = a;
        }

        // ---- gating epilogue: 4 rows per lane, 8 fused transcendentals/elem ----
#pragma unroll
        for (int r = 0; r < 4; r++) {
          int m = quad * 4 + r;                   // C/D row mapping (m89)
          float xv = (float)Ash[m][f];
          float sf = acc[0][r] + bias[0];
          float lg = acc[1][r] + bias[1];
          float lf = acc[2][r] + bias[2];
          float of = acc[3][r] + bias[3];
          // xv * sigm(sf)
          float e0 = __builtin_amdgcn_exp2f(-LOG2E * sf);
          float t1 = xv * __builtin_amdgcn_rcpf(1.0f + e0);
          // tanh(lg)*sigm(lf) = (e1-1)/((e1+1)*(1+e2))
          float e1 = __builtin_amdgcn_exp2f((2.0f * LOG2E) * lg);
          float e2 = __builtin_amdgcn_exp2f(-LOG2E * lf);
          float t2 = (e1 - 1.0f) * __builtin_amdgcn_rcpf((e1 + 1.0f) * (1.0f + e2));
          float nr = t1 + t2;
          // tanh(nr)*sigm(of)
          float e3 = __builtin_amdgcn_exp2f((2.0f * LOG2E) * nr);
          float e4 = __builtin_amdgcn_exp2f(-LOG2E * of);
          float xn = (e3 - 1.0f) * __builtin_amdgcn_rcpf((e3 + 1.0f) * (1.0f + e4));
          if ((mybits >> r) & 1) {
            if (l == 0) {
              Ash[m][f] = (f16)xn;                // layer-1 input (this wave's 32 cols)
            } else {
              outPtr[(size_t)s_tok[m] * D + f] = xn;
            }
          }
        }
      }
      if (l == 0) {
        __syncthreads();   // pass barrier B: all l=0 Ash writes done
        LOAD_AF();         // reload full-K A fragments for layer 1
      }
    }
  }
#undef LOAD_AF
}

extern "C" void kernel_launch(void* const* d_in, const int* in_sizes, int n_in,
                              void* d_out, int out_size, void* d_ws, size_t ws_size,
                              hipStream_t stream) {
  const int*   pos = (const int*)d_in[0];
  const float* x   = (const float*)d_in[1];
  const float* Ws  = (const float*)d_in[2];
  const float* bs  = (const float*)d_in[3];
  float* out = (float*)d_out;
  int* wsI = (int*)d_ws;
  f16* Wf = (f16*)((char*)d_ws + WS_WF_OFF);

  k_prep  <<<544, 256, 0, stream>>>(Ws, pos, wsI, Wf);
  k_assign<<<NHB, 256, 0, stream>>>(pos, wsI);
  k_main  <<<NTILES, 256, 0, stream>>>(x, bs, wsI, Wf, out);
}

// Round 10
// 136.110 us; speedup vs baseline: 1.0407x; 1.0407x over previous
//
#include <hip/hip_runtime.h>
#include <hip/hip_fp16.h>
#include <stdint.h>

// Problem constants (fixed by reference file)
#define TOKENS 65536   // T*B = 2048*32
#define D      128
#define NEXP   9       // MULTI_INFER_NUM + 1
#define MT     32      // tokens per tile; NO padding -> grid exactly TOKENS/MT
#define NTILES (TOKENS / MT)   // 2048
#define NHB    256     // hist blocks (TOKENS/256)

typedef _Float16 f16;
typedef _Float16 f16x8  __attribute__((ext_vector_type(8)));
typedef float    f32x4  __attribute__((ext_vector_type(4)));
typedef uint32_t u32;
typedef unsigned long long u64;

// ---- workspace layout (int32 indices) ----
#define WI_TOKOFF  32            // [10] exclusive token offsets per expert
#define WI_HIST    128           // [256][9]
#define WI_PERM    4736          // [TOKENS]
#define WS_WF_OFF  ((4736 + TOKENS) * 4)   // f16 Wfrag[72][16384], 16B-aligned

#define LOG2E  1.44269504f

// ---- fused prep: fragment-major f16 weights for 16x16x32 (blocks 0..287) + hist (288..543) ----
// Wf[mat][c(8)][kb(4)][lane(64)][i(8)], lane = quad*16 + n:
//   element = Ws[mat][d = kb*32 + quad*8 + i][f = c*16 + n]
__global__ void k_prep(const float* __restrict__ Ws, const int* __restrict__ pos,
                       int* __restrict__ wsI, f16* __restrict__ Wf) {
  const int tid = threadIdx.x;
  if (blockIdx.x < 288) {
    const int mat = blockIdx.x >> 2;      // 0..71
    const int q   = blockIdx.x & 3;
    const float* src = Ws + (size_t)mat * (D * D);
    f16* dst = Wf + (size_t)mat * (D * D);
#pragma unroll
    for (int p = 0; p < 2; ++p) {
      int cc = q * 512 + p * 256 + tid;   // 16B chunk index 0..2047 = ((c*4+kb)*64 + lane)
      int ln = cc & 63;
      int kb = (cc >> 6) & 3;
      int c  = cc >> 8;
      int quad = ln >> 4, n = ln & 15;
      int f  = c * 16 + n;
      int d0 = kb * 32 + quad * 8;
      f16x8 w;
#pragma unroll
      for (int i = 0; i < 8; ++i) w[i] = (f16)src[(d0 + i) * D + f];
      *(f16x8*)(dst + cc * 8) = w;
    }
  } else {
    const int b = blockIdx.x - 288;
    __shared__ int h[NEXP];
    if (tid < NEXP) h[tid] = 0;
    __syncthreads();
    int e = pos[b * 256 + tid]; e = e < 8 ? e : 8;
    atomicAdd(&h[e], 1);
    __syncthreads();
    if (tid < NEXP) wsI[WI_HIST + b * NEXP + tid] = h[tid];
  }
}

// ---- assignment WITH fused scan: each block derives expert totals + its own prefix
//      from the histogram (no separate k_scan launch, no global atomics) ----
__global__ void k_assign(const int* __restrict__ pos, int* __restrict__ wsI) {
  const int tid = threadIdx.x, b = blockIdx.x;
  const int lane = tid & 63, w = tid >> 6;
  __shared__ int redF[4], redP[4];
  __shared__ int totS[NEXP], relS[NEXP];
  __shared__ int waveCnt[4][NEXP];
  __shared__ int waveBase[4][NEXP];

  // per-expert: total over all 256 hist blocks + prefix over blocks < b
#pragma unroll 1
  for (int e = 0; e < NEXP; ++e) {
    int v  = wsI[WI_HIST + tid * NEXP + e];
    int vp = (tid < b) ? v : 0;
#pragma unroll
    for (int off = 32; off; off >>= 1) {
      v  += __shfl_down(v, off);
      vp += __shfl_down(vp, off);
    }
    if (lane == 0) { redF[w] = v; redP[w] = vp; }
    __syncthreads();
    if (tid == 0) {
      totS[e] = redF[0] + redF[1] + redF[2] + redF[3];
      relS[e] = redP[0] + redP[1] + redP[2] + redP[3];
    }
    __syncthreads();
  }

  // block 0 publishes expert token offsets for k_main
  if (b == 0 && tid == 0) {
    int tok = 0; wsI[WI_TOKOFF] = 0;
#pragma unroll
    for (int e = 0; e < NEXP; ++e) { tok += totS[e]; wsI[WI_TOKOFF + e + 1] = tok; }
  }

  int e = pos[b * 256 + tid]; e = e < 8 ? e : 8;
  int myRank = 0;
#pragma unroll
  for (int ee = 0; ee < NEXP; ++ee) {
    u64 m = __ballot(e == ee);
    if (e == ee) myRank = __popcll(m & ((1ull << lane) - 1ull));
    if (lane == 0) waveCnt[w][ee] = __popcll(m);
  }
  __syncthreads();
  if (tid < NEXP) {
    int s = 0;
#pragma unroll
    for (int w2 = 0; w2 < 4; ++w2) { waveBase[w2][tid] = s; s += waveCnt[w2][tid]; }
  }
  __syncthreads();
  int tokoff = 0;
#pragma unroll
  for (int k = 0; k < NEXP; ++k) tokoff += (k < e) ? totS[k] : 0;
  wsI[WI_PERM + tokoff + relS[e] + waveBase[w][e] + myRank] = b * 256 + tid;
}

// ---- fused main: R5 structure (MT=32, 4 waves x 32r x 32c, double-buffered B,
//      ~96 unified regs -> 4 waves/SIMD) + exact-2048 masked grid + fused 8-trans
//      epilogue. Boundary blocks (<=8) multi-pass with 32-bit row mask. ----
__launch_bounds__(256, 4)
__global__ void k_main(const float* __restrict__ xin, const float* __restrict__ bsPtr,
                       const int* __restrict__ wsI, const f16* __restrict__ Wf,
                       float* __restrict__ outPtr) {
  __shared__ __attribute__((aligned(16))) f16 Ash[MT][136];   // 32 x 272B
  __shared__ int s_tok[MT];
  __shared__ int s_e[MT];
  __shared__ int s_list[NEXP];
  __shared__ int s_npass;

  const int tid = threadIdx.x;
  const int bid = blockIdx.x;                 // 0..2047, tile = rows bid*32..+31 of perm
  const int lane = tid & 63;

  // ---- wave 0 (lanes 0..31 = rows): token ids, per-row expert, distinct-expert run list ----
  if (tid < 64) {
    int mm = lane & 31;
    int row = bid * MT + mm;
    int tok0 = wsI[WI_PERM + row];
    int ee = 0;
#pragma unroll
    for (int k = 1; k < NEXP; ++k) ee += (row >= wsI[WI_TOKOFF + k]);
    if (lane < 32) { s_tok[mm] = tok0; s_e[mm] = ee; }
    int eprev = __shfl_up(ee, 1);
    bool newrun = (lane < 32) && (lane == 0 || ee != eprev);
    u64 runs = __ballot(newrun);
    if (newrun) s_list[__popcll(runs & ((1ull << lane) - 1ull))] = ee;
    if (lane == 0) s_npass = (int)__popcll(runs);
  }

  // ---- stage A (32 rows) as f16 via perm gather ----
  {
    int m = tid >> 3, h = tid & 7;            // thread covers cols h*16..h*16+15
    int tok = wsI[WI_PERM + bid * MT + m];
    const float4* src = (const float4*)(xin + (size_t)tok * D + h * 16);
    f16* drow = &Ash[m][h * 16];
#pragma unroll
    for (int i = 0; i < 2; i++) {
      float4 a = src[2 * i], b2 = src[2 * i + 1];
      f16x8 wv;
      wv[0] = (f16)a.x;  wv[1] = (f16)a.y;  wv[2] = (f16)a.z;  wv[3] = (f16)a.w;
      wv[4] = (f16)b2.x; wv[5] = (f16)b2.y; wv[6] = (f16)b2.z; wv[7] = (f16)b2.w;
      *(f16x8*)&drow[i * 8] = wv;
    }
  }
  __syncthreads();   // barrier 1: Ash, s_tok, s_e, s_list staged

  const int n    = lane & 15;       // MFMA col
  const int quad = lane >> 4;       // k-quad / row-quad
  const int cBase = (tid >> 6) * 2; // wave's first 16-col chunk (4 waves cover 128 cols)
  const int vlane = lane * 8;       // B-frag lane offset (f16 elems)
  const int npass = __builtin_amdgcn_readfirstlane(s_npass);

  f16x8 aF0[4], aF1[4];             // A fragments: rows 0-15 / 16-31, full K=128
  f16x8 b0[4], b1[4];
  f32x4 acc[4][2];                  // [gate][subtile]

#define LOAD_AF()                                                              \
  do {                                                                         \
    _Pragma("unroll")                                                          \
    for (int _kb = 0; _kb < 4; ++_kb) {                                        \
      aF0[_kb] = *(const f16x8*)&Ash[n][_kb * 32 + quad * 8];                  \
      aF1[_kb] = *(const f16x8*)&Ash[16 + n][_kb * 32 + quad * 8];             \
    }                                                                          \
  } while (0)

#define PREFETCH_B(BUF, LL, CC, JJ)                                            \
  do {                                                                         \
    if ((LL) < 2) {                                                            \
      const f16* _p = We + ((LL) * 4 + (JJ)) * 147456 + (CC) * 2048 + vlane;   \
      _Pragma("unroll")                                                        \
      for (int _kb = 0; _kb < 4; ++_kb)                                        \
        BUF[_kb] = *(const f16x8*)(_p + _kb * 512);                            \
    }                                                                          \
  } while (0)

#define MFMA2(G, BUF)                                                          \
  do {                                                                         \
    f32x4 _x = {0.f, 0.f, 0.f, 0.f}, _y = {0.f, 0.f, 0.f, 0.f};                \
    _Pragma("unroll")                                                          \
    for (int _kb = 0; _kb < 4; ++_kb) {                                        \
      _x = __builtin_amdgcn_mfma_f32_16x16x32_f16(aF0[_kb], BUF[_kb], _x, 0, 0, 0); \
      _y = __builtin_amdgcn_mfma_f32_16x16x32_f16(aF1[_kb], BUF[_kb], _y, 0, 0, 0); \
    }                                                                          \
    acc[G][0] = _x; acc[G][1] = _y;                                            \
  } while (0)

#pragma unroll 1
  for (int p = 0; p < npass; ++p) {
    const int E = __builtin_amdgcn_readfirstlane(s_list[p]);
    const f16* We = Wf + (size_t)E * 16384;       // mat stride = 9*16384 = 147456
    // 32-bit row mask: bit m set iff tile-row m belongs to expert E
    const u32 rowmask = (u32)__ballot(lane < 32 && s_e[lane] == E);
    const u32 mybits = rowmask >> (quad * 4);     // bit (s*16+r) tests row s*16+quad*4+r

    LOAD_AF();
    PREFETCH_B(b0, 0, cBase, 0);
    __syncthreads();   // pass barrier A: all aF(l=0) reads done before any Ash write

#pragma unroll 1
    for (int l = 0; l < 2; l++) {
#pragma unroll 1
      for (int ci = 0; ci < 2; ci++) {
        const int cc = cBase + ci;
        const int f = cc * 16 + n;
        float bias[4];
#pragma unroll
        for (int j = 0; j < 4; j++)
          bias[j] = bsPtr[((l * 4 + j) * NEXP + E) * D + f];

        const int ln = (ci == 1) ? l + 1 : l;     // next stage (j=0) coords
        const int cn = (ci == 1) ? cBase : cc + 1;

        PREFETCH_B(b1, l, cc, 1);  MFMA2(0, b0);
        PREFETCH_B(b0, l, cc, 2);  MFMA2(1, b1);
        PREFETCH_B(b1, l, cc, 3);  MFMA2(2, b0);
        PREFETCH_B(b0, ln, cn, 0); MFMA2(3, b1);

        // ---- gating epilogue: 2 subtiles x 4 rows per lane, fused 8-trans, masked ----
#pragma unroll
        for (int s = 0; s < 2; s++) {
#pragma unroll
          for (int r = 0; r < 4; r++) {
            int m = s * 16 + quad * 4 + r;        // C/D row mapping (m89)
            float xv = (float)Ash[m][f];
            float sf = acc[0][s][r] + bias[0];
            float lg = acc[1][s][r] + bias[1];
            float lf = acc[2][s][r] + bias[2];
            float of = acc[3][s][r] + bias[3];
            // xv * sigm(sf)
            float e0 = __builtin_amdgcn_exp2f(-LOG2E * sf);
            float t1 = xv * __builtin_amdgcn_rcpf(1.0f + e0);
            // tanh(lg)*sigm(lf) = (e1-1)/((e1+1)*(1+e2))
            float e1 = __builtin_amdgcn_exp2f((2.0f * LOG2E) * lg);
            float e2 = __builtin_amdgcn_exp2f(-LOG2E * lf);
            float t2 = (e1 - 1.0f) * __builtin_amdgcn_rcpf((e1 + 1.0f) * (1.0f + e2));
            float nr = t1 + t2;
            // tanh(nr)*sigm(of)
            float e3 = __builtin_amdgcn_exp2f((2.0f * LOG2E) * nr);
            float e4 = __builtin_amdgcn_exp2f(-LOG2E * of);
            float xn = (e3 - 1.0f) * __builtin_amdgcn_rcpf((e3 + 1.0f) * (1.0f + e4));
            if ((mybits >> (s * 16 + r)) & 1) {
              if (l == 0) {
                Ash[m][f] = (f16)xn;              // layer-1 input (this wave's 32 cols)
              } else {
                outPtr[(size_t)s_tok[m] * D + f] = xn;
              }
            }
          }
        }
      }
      if (l == 0) {
        __syncthreads();   // pass barrier B: all l=0 Ash writes done
        LOAD_AF();         // reload full-K A fragments for layer 1
      }
    }
  }
#undef LOAD_AF
#undef PREFETCH_B
#undef MFMA2
}

extern "C" void kernel_launch(void* const* d_in, const int* in_sizes, int n_in,
                              void* d_out, int out_size, void* d_ws, size_t ws_size,
                              hipStream_t stream) {
  const int*   pos = (const int*)d_in[0];
  const float* x   = (const float*)d_in[1];
  const float* Ws  = (const float*)d_in[2];
  const float* bs  = (const float*)d_in[3];
  float* out = (float*)d_out;
  int* wsI = (int*)d_ws;
  f16* Wf = (f16*)((char*)d_ws + WS_WF_OFF);

  k_prep  <<<544, 256, 0, stream>>>(Ws, pos, wsI, Wf);
  k_assign<<<NHB, 256, 0, stream>>>(pos, wsI);
  k_main  <<<NTILES, 256, 0, stream>>>(x, bs, wsI, Wf, out);
}